// Round 1
// baseline (370.045 us; speedup 1.0000x reference)
//
#include <hip/hip_runtime.h>

#define NUM_BEAM 24
#define NUM_BIN  257
#define NUM_CH   8
#define N_FRAMES 16384

// input:   (F, 2, NUM_BIN, NUM_CH) f32
// W:       (NUM_BEAM, 2, NUM_BIN, NUM_CH) f32
// beam_id: (F,) int
// out:     (F, 2, NUM_BIN, 1) f32
__global__ __launch_bounds__(256) void Beamformor_89653147336805_kernel(
    const float* __restrict__ input,
    const float* __restrict__ W,
    const int*   __restrict__ beam_id,
    float*       __restrict__ out)
{
    const int total = N_FRAMES * NUM_BIN;
    int idx = blockIdx.x * blockDim.x + threadIdx.x;
    if (idx >= total) return;

    int f = idx / NUM_BIN;           // compiler emits magic-mul for /257
    int b = idx - f * NUM_BIN;

    int beam = beam_id[f];

    const size_t f_base = (size_t)f    * (2 * NUM_BIN * NUM_CH);
    const size_t w_base = (size_t)beam * (2 * NUM_BIN * NUM_CH);
    const int    plane  = NUM_BIN * NUM_CH;   // 2056 floats
    const int    boff   = b * NUM_CH;         // 32B-aligned

    const float4* xr = (const float4*)(input + f_base + boff);
    const float4* xi = (const float4*)(input + f_base + plane + boff);
    const float4* wr = (const float4*)(W + w_base + boff);
    const float4* wi = (const float4*)(W + w_base + plane + boff);

    float4 xr0 = xr[0], xr1 = xr[1];
    float4 xi0 = xi[0], xi1 = xi[1];
    float4 wr0 = wr[0], wr1 = wr[1];
    float4 wi0 = wi[0], wi1 = wi[1];

    // out_r = sum(xr*wr + xi*wi); out_i = sum(xi*wr - xr*wi)
    float out_r =
        xr0.x * wr0.x + xr0.y * wr0.y + xr0.z * wr0.z + xr0.w * wr0.w +
        xr1.x * wr1.x + xr1.y * wr1.y + xr1.z * wr1.z + xr1.w * wr1.w +
        xi0.x * wi0.x + xi0.y * wi0.y + xi0.z * wi0.z + xi0.w * wi0.w +
        xi1.x * wi1.x + xi1.y * wi1.y + xi1.z * wi1.z + xi1.w * wi1.w;

    float out_i =
        xi0.x * wr0.x + xi0.y * wr0.y + xi0.z * wr0.z + xi0.w * wr0.w +
        xi1.x * wr1.x + xi1.y * wr1.y + xi1.z * wr1.z + xi1.w * wr1.w -
        xr0.x * wi0.x - xr0.y * wi0.y - xr0.z * wi0.z - xr0.w * wi0.w -
        xr1.x * wi1.x - xr1.y * wi1.y - xr1.z * wi1.z - xr1.w * wi1.w;

    // out layout: (F, 2, NUM_BIN, 1) -> f*2*257 + p*257 + b
    size_t o_base = (size_t)f * (2 * NUM_BIN) + b;
    out[o_base]           = out_r;
    out[o_base + NUM_BIN] = out_i;
}

extern "C" void kernel_launch(void* const* d_in, const int* in_sizes, int n_in,
                              void* d_out, int out_size, void* d_ws, size_t ws_size,
                              hipStream_t stream) {
    const float* input   = (const float*)d_in[0];
    const float* W       = (const float*)d_in[1];
    const int*   beam_id = (const int*)d_in[2];
    float* out = (float*)d_out;

    const int total  = N_FRAMES * NUM_BIN;           // 4,210,688
    const int block  = 256;
    const int grid   = (total + block - 1) / block;  // 16448

    Beamformor_89653147336805_kernel<<<grid, block, 0, stream>>>(input, W, beam_id, out);
}